// Round 8
// baseline (250.237 us; speedup 1.0000x reference)
//
#include <hip/hip_runtime.h>

#define LQ 4096
#define CH 128
#define NB 4
// log2(e)/sqrt(128): folded into Q so softmax = exp2(S)
#define QSCALE 0.12753139626233174f
#define MAXCH 8
#define TILE_HW 8192   // one 64-key tile in fragment-slot order: 16 KB = 8192 ushort

#if defined(__has_builtin)
#if __has_builtin(__builtin_amdgcn_mfma_f32_16x16x16bf16_1k)
#define HAVE_MFMA16 1
#endif
#endif

typedef __attribute__((ext_vector_type(8))) unsigned short ushort8;
typedef __attribute__((ext_vector_type(4))) unsigned short ushort4v;
typedef __attribute__((ext_vector_type(4))) short short4v;
typedef __attribute__((ext_vector_type(8))) __bf16 bf16x8;
typedef __attribute__((ext_vector_type(4))) float f32x4;

__device__ inline unsigned short f2bf(float f) {
    unsigned int u = __builtin_bit_cast(unsigned int, f);
    u += 0x7fffu + ((u >> 16) & 1u);   // round-to-nearest-even
    return (unsigned short)(u >> 16);
}
__device__ inline float bf2f(unsigned short h) {
    unsigned int u = (unsigned int)h << 16;
    return __builtin_bit_cast(float, u);
}
// pack two positive floats to bf16 pair, round-half-up
__device__ inline unsigned int bfpack2(float a, float b) {
    unsigned int ua = __builtin_bit_cast(unsigned int, a) + 0x8000u;
    unsigned int ub = __builtin_bit_cast(unsigned int, b) + 0x8000u;
    return (ua >> 16) | (ub & 0xffff0000u);
}
// async 16B/lane global->LDS DMA: dest = lds_base + lane*16 (wave-uniform base)
__device__ inline void gload_lds16(const unsigned short* g, unsigned short* l) {
    __builtin_amdgcn_global_load_lds(
        (const __attribute__((address_space(1))) unsigned int*)(g),
        (__attribute__((address_space(3))) unsigned int*)(l), 16, 0, 0);
}

// ---------------------------------------------------------------------------
// Kernel 1: v = W_kv @ x (+bias), MFMA; emit Vt2/Vc2 in FRAGMENT-SLOT order:
//   Vt2[b][T][g=nt*4+kc][lane=quad*16+l16] (16B) = V[t=64T+16nt+l16][c=32kc+8quad..+8]
//   Vc2[b][T][g=nt*4+p ][lane]             (16B) = [V[c=32p+l16][t4] | V[c=32p+16+l16][t4]],
//                                                   t4 = 64T+16nt+4quad..+4
// so attn can DMA them straight into LDS and read b128 at base+lane*16.
// ---------------------------------------------------------------------------
__global__ __launch_bounds__(256) void prep_kernel(
    const float* __restrict__ x, const float* __restrict__ Wkv,
    const float* __restrict__ bkv,
    unsigned short* __restrict__ Vt2, unsigned short* __restrict__ Vc2)
{
    __shared__ __align__(16) unsigned short xs[64 * 136];  // [l][c] bf16
    __shared__ __align__(16) unsigned short vs[128 * 72];  // [o][l] bf16
    const int tid = threadIdx.x;
    const int lane = tid & 63;
    const int wave = tid >> 6;
    const int quad = lane >> 4, l16 = lane & 15;
    const int b = blockIdx.x & 3;
    const int T = blockIdx.x >> 2;
    const int l0 = T << 6;

    {   // stage x tile transposed: [64 l][128 c] bf16 (coalesced f32x4 loads)
        const f32x4* xg4 = (const f32x4*)(x + (size_t)b * CH * LQ + l0);
        #pragma unroll
        for (int i = 0; i < 8; ++i) {
            int idx = i * 256 + tid;          // 2048 chunks: c(128) x l4(16)
            int c = idx >> 4, l4 = idx & 15;
            f32x4 v = xg4[c * (LQ / 4) + l4];
            #pragma unroll
            for (int m = 0; m < 4; ++m) xs[(l4 * 4 + m) * 136 + c] = f2bf(v[m]);
        }
    }
    __syncthreads();

    const int wo = wave * 32;
    f32x4 acc[2][4];   // [ot][lt]
    #pragma unroll
    for (int ot = 0; ot < 2; ++ot)
        #pragma unroll
        for (int lt = 0; lt < 4; ++lt) acc[ot][lt] = f32x4{0.f, 0.f, 0.f, 0.f};

    #pragma unroll
    for (int kc = 0; kc < 4; ++kc) {
        bf16x8 af[2];
        #pragma unroll
        for (int ot = 0; ot < 2; ++ot) {
            const float* wrow = Wkv + (size_t)(wo + ot * 16 + l16) * CH + kc * 32 + quad * 8;
            ushort8 a;
            #pragma unroll
            for (int j = 0; j < 8; ++j) a[j] = f2bf(wrow[j]);
            af[ot] = __builtin_bit_cast(bf16x8, a);
        }
        #pragma unroll
        for (int lt = 0; lt < 4; ++lt) {
            bf16x8 bf = __builtin_bit_cast(bf16x8,
                *(const ushort8*)(xs + (lt * 16 + l16) * 136 + kc * 32 + quad * 8));
            #pragma unroll
            for (int ot = 0; ot < 2; ++ot)
                acc[ot][lt] = __builtin_amdgcn_mfma_f32_16x16x32_bf16(af[ot], bf, acc[ot][lt], 0, 0, 0);
        }
    }
    // bias + stage to vs[o][l] (C-layout: o = wo+ot*16+quad*4+r, l = lt*16+l16)
    #pragma unroll
    for (int ot = 0; ot < 2; ++ot) {
        float bias[4];
        #pragma unroll
        for (int r = 0; r < 4; ++r) bias[r] = bkv[wo + ot * 16 + quad * 4 + r];
        #pragma unroll
        for (int lt = 0; lt < 4; ++lt)
            #pragma unroll
            for (int r = 0; r < 4; ++r)
                vs[(wo + ot * 16 + quad * 4 + r) * 72 + lt * 16 + l16] =
                    f2bf(acc[ot][lt][r] + bias[r]);
    }
    __syncthreads();
    const size_t tbase = ((size_t)b * 64 + T) * TILE_HW;
    // Vt2: 1024 16B-chunks, 4/thread, consecutive tid -> consecutive 16B (coalesced)
    #pragma unroll
    for (int i = 0; i < 4; ++i) {
        const int ci = i * 256 + tid;
        const int g = ci >> 6, ls = ci & 63;
        const int nt = g >> 2, kc = g & 3, qs = ls >> 4, l16s = ls & 15;
        ushort8 v;
        #pragma unroll
        for (int j = 0; j < 8; ++j) v[j] = vs[(kc * 32 + qs * 8 + j) * 72 + nt * 16 + l16s];
        *(ushort8*)(Vt2 + tbase + (size_t)ci * 8) = v;
    }
    // Vc2: 1024 16B-chunks, nc-paired
    #pragma unroll
    for (int i = 0; i < 4; ++i) {
        const int ci = i * 256 + tid;
        const int g = ci >> 6, ls = ci & 63;
        const int nt = g >> 2, p = g & 3, qs = ls >> 4, l16s = ls & 15;
        ushort4v a = *(const ushort4v*)(vs + (p * 32 + l16s) * 72 + nt * 16 + qs * 4);
        ushort4v c2 = *(const ushort4v*)(vs + (p * 32 + 16 + l16s) * 72 + nt * 16 + qs * 4);
        ushort8 v;
        #pragma unroll
        for (int j = 0; j < 4; ++j) { v[j] = a[j]; v[j + 4] = c2[j]; }
        *(ushort8*)(Vc2 + tbase + (size_t)ci * 8) = v;
    }
}

// ---------------------------------------------------------------------------
// Kernel 2: flash attention, split-K, mt=4 (wave owns 64 q), transposed-S
// chain (r6-verified math). Tiles arrive via global_load_lds DMA in
// fragment-slot order (double-buffered, ONE barrier per iter); every LDS
// read is ds_read_b128 at group_base + lane*16 (conflict-free).
// ---------------------------------------------------------------------------
__global__ __launch_bounds__(256, 2) void attn_kernel(
    const float* __restrict__ x, const unsigned short* __restrict__ Vt2,
    const unsigned short* __restrict__ Vc2,
    unsigned short* __restrict__ Opart, float* __restrict__ Lsum, int titers)
{
    __shared__ __align__(16) unsigned short bufA[2][TILE_HW];  // 32 KB
    __shared__ __align__(16) unsigned short bufB[2][TILE_HW];  // 32 KB
    const int tid = threadIdx.x;
    const int wave = tid >> 6, lane = tid & 63;
    const int quad = lane >> 4, l16 = lane & 15;
    const int b = blockIdx.x & 3;
    const int rest = blockIdx.x >> 2;
    const int qtile = rest & 15;           // 16 tiles of 256 q
    const int chunk = rest >> 4;           // nchunk split-K chunks
    const int q0w = (qtile << 8) + (wave << 6);
    const int Tbase = chunk * titers;

    const unsigned short* vtb = Vt2 + (size_t)b * 64 * TILE_HW;
    const unsigned short* vcb = Vc2 + (size_t)b * 64 * TILE_HW;

    // Q B-frags from x: B[n=l16 -> q][k=quad*8+j -> c], scaled (one-time)
    bf16x8 qf[4][4];
    #pragma unroll
    for (int mt = 0; mt < 4; ++mt)
        #pragma unroll
        for (int kc = 0; kc < 4; ++kc) {
            ushort8 v;
            #pragma unroll
            for (int j = 0; j < 8; ++j) {
                int c = kc * 32 + quad * 8 + j;
                v[j] = f2bf(x[((size_t)b * CH + c) * LQ + q0w + mt * 16 + l16] * QSCALE);
            }
            qf[mt][kc] = __builtin_bit_cast(bf16x8, v);
        }

    f32x4 oacc[4][8];
    #pragma unroll
    for (int mt = 0; mt < 4; ++mt)
        #pragma unroll
        for (int i = 0; i < 8; ++i) oacc[mt][i] = f32x4{0.f, 0.f, 0.f, 0.f};
    float lsum[4] = {0.f, 0.f, 0.f, 0.f};

    // DMA issue: wave w stages groups w*4..w*4+3 of each tensor (8 instr/wave)
    auto issue = [&](int T, int nb) {
        const unsigned short* sa = vtb + (size_t)T * TILE_HW + lane * 8;
        const unsigned short* sb = vcb + (size_t)T * TILE_HW + lane * 8;
        #pragma unroll
        for (int g = 0; g < 4; ++g) {
            const int go = (wave * 4 + g) * 512;
            gload_lds16(sa + go, &bufA[nb][go]);
            gload_lds16(sb + go, &bufB[nb][go]);
        }
    };
    issue(Tbase, 0);

    for (int it = 0; it < titers; ++it) {
        __syncthreads();   // drains own DMA (vmcnt0) + publishes buf[it&1]
        if (it + 1 < titers) issue(Tbase + it + 1, (it + 1) & 1);
        const unsigned short* A = bufA[it & 1];
        const unsigned short* B = bufB[it & 1];
        #pragma unroll
        for (int nt = 0; nt < 4; ++nt) {
            // V A-frags: conflict-free b128 at group base + lane*16
            bf16x8 vA[4];
            #pragma unroll
            for (int kc = 0; kc < 4; ++kc)
                vA[kc] = __builtin_bit_cast(bf16x8,
                    *(const ushort8*)(A + (nt * 4 + kc) * 512 + lane * 8));
            // S^T: D[m=t][n=q]; lane: q=l16, t=nt*16+quad*4+r
            f32x4 s[4];
            #pragma unroll
            for (int mt = 0; mt < 4; ++mt) {
                s[mt] = f32x4{0.f, 0.f, 0.f, 0.f};
                #pragma unroll
                for (int kc = 0; kc < 4; ++kc)
                    s[mt] = __builtin_amdgcn_mfma_f32_16x16x32_bf16(vA[kc], qf[mt][kc], s[mt], 0, 0, 0);
            }
            // exp2 + pack P as PV A-operand (k=quad*4+j matches t layout)
#ifdef HAVE_MFMA16
            short4v pf[4];
#else
            bf16x8 pf[4];
#endif
            #pragma unroll
            for (int mt = 0; mt < 4; ++mt) {
                float p0 = __builtin_amdgcn_exp2f(s[mt][0]);
                float p1 = __builtin_amdgcn_exp2f(s[mt][1]);
                float p2 = __builtin_amdgcn_exp2f(s[mt][2]);
                float p3 = __builtin_amdgcn_exp2f(s[mt][3]);
                lsum[mt] += (p0 + p1) + (p2 + p3);
                unsigned int lo = bfpack2(p0, p1);
                unsigned int hi = bfpack2(p2, p3);
#ifdef HAVE_MFMA16
                ushort4v pk;
                pk[0] = (unsigned short)lo; pk[1] = (unsigned short)(lo >> 16);
                pk[2] = (unsigned short)hi; pk[3] = (unsigned short)(hi >> 16);
                pf[mt] = __builtin_bit_cast(short4v, pk);
#else
                ushort8 pk;
                pk[0] = (unsigned short)lo; pk[1] = (unsigned short)(lo >> 16);
                pk[2] = (unsigned short)hi; pk[3] = (unsigned short)(hi >> 16);
                pk[4] = 0; pk[5] = 0; pk[6] = 0; pk[7] = 0;
                pf[mt] = __builtin_bit_cast(bf16x8, pk);
#endif
            }
            // PV: nc-paired b128 reads; B[k=quad*4+j][n=c=l16]
            #pragma unroll
            for (int p = 0; p < 4; ++p) {
                ushort8 d8 = *(const ushort8*)(B + (nt * 4 + p) * 512 + lane * 8);
                #pragma unroll
                for (int h = 0; h < 2; ++h) {
                    ushort4v f;
                    #pragma unroll
                    for (int j = 0; j < 4; ++j) f[j] = d8[h * 4 + j];
#ifdef HAVE_MFMA16
                    short4v vB = __builtin_bit_cast(short4v, f);
                    #pragma unroll
                    for (int mt = 0; mt < 4; ++mt)
                        oacc[mt][p * 2 + h] = __builtin_amdgcn_mfma_f32_16x16x16bf16_1k(
                            pf[mt], vB, oacc[mt][p * 2 + h], 0, 0, 0);
#else
                    ushort8 vb;
                    #pragma unroll
                    for (int j = 0; j < 4; ++j) { vb[j] = f[j]; vb[j + 4] = 0; }
                    bf16x8 vB = __builtin_bit_cast(bf16x8, vb);
                    #pragma unroll
                    for (int mt = 0; mt < 4; ++mt)
                        oacc[mt][p * 2 + h] = __builtin_amdgcn_mfma_f32_16x16x32_bf16(
                            pf[mt], vB, oacc[mt][p * 2 + h], 0, 0, 0);
#endif
                }
            }
        }
    }
    // ---- Lsum: per-lane partial (q=l16), reduce across the 4 quads ----
    const size_t pbase = ((size_t)(chunk * NB + b) * LQ);
    #pragma unroll
    for (int mt = 0; mt < 4; ++mt) {
        float v = lsum[mt];
        v += __shfl_xor(v, 16);
        v += __shfl_xor(v, 32);
        if (lane < 16) Lsum[pbase + q0w + mt * 16 + lane] = v;
    }
    // ---- partials: Opart[ch][b][q][c] (bf16); oacc lane: q=quad*4+r, c=l16
    #pragma unroll
    for (int mt = 0; mt < 4; ++mt)
        #pragma unroll
        for (int r = 0; r < 4; ++r) {
            const int q = q0w + mt * 16 + quad * 4 + r;
            unsigned short* orow = Opart + (pbase + q) * CH + l16;
            #pragma unroll
            for (int nc = 0; nc < 8; ++nc) orow[nc * 16] = f2bf(oacc[mt][nc][r]);
        }
}

// ---------------------------------------------------------------------------
// Kernel 3: out[b][c][q] = sum_ch Opart[ch][b][q][c] / sum_ch Lsum[ch][b][q]
// 512 blocks: (b, 32-q tile). LDS transpose.
// ---------------------------------------------------------------------------
__global__ __launch_bounds__(256) void combine_kernel(
    const unsigned short* __restrict__ Opart, const float* __restrict__ Lsum,
    float* __restrict__ out, int nchunk)
{
    __shared__ __align__(16) float ls[32 * 132];   // [q][c] padded
    __shared__ float linv[32];
    const int tid = threadIdx.x;
    const int b = blockIdx.x & 3;
    const int q0 = (blockIdx.x >> 2) << 5;

    if (tid < 32) {
        float s = 0.f;
        for (int ch = 0; ch < nchunk; ++ch) s += Lsum[(size_t)(ch * NB + b) * LQ + q0 + tid];
        linv[tid] = 1.0f / s;
    }
    __syncthreads();
    {
        const int c8 = (tid & 15) * 8, qg = tid >> 4;   // 16 q-groups x 2 q
        #pragma unroll
        for (int i = 0; i < 2; ++i) {
            const int q = qg * 2 + i;
            float s[8];
            #pragma unroll
            for (int k = 0; k < 8; ++k) s[k] = 0.f;
            for (int ch = 0; ch < nchunk; ++ch) {
                ushort8 p = *(const ushort8*)(Opart +
                    ((size_t)(ch * NB + b) * LQ + q0 + q) * CH + c8);
                #pragma unroll
                for (int k = 0; k < 8; ++k) s[k] += bf2f(p[k]);
            }
            const float li = linv[q];
            f32x4 o0, o1;
            #pragma unroll
            for (int k = 0; k < 4; ++k) { o0[k] = s[k] * li; o1[k] = s[k + 4] * li; }
            *(f32x4*)(ls + q * 132 + c8) = o0;
            *(f32x4*)(ls + q * 132 + c8 + 4) = o1;
        }
    }
    __syncthreads();
    {
        const int c = tid & 127, qh = tid >> 7;   // 2 halves of 16 q
        float* dst = out + ((size_t)b * CH + c) * LQ + q0 + qh * 16;
        #pragma unroll
        for (int i = 0; i < 4; ++i) {
            f32x4 o;
            #pragma unroll
            for (int r = 0; r < 4; ++r) o[r] = ls[(qh * 16 + i * 4 + r) * 132 + c];
            ((f32x4*)dst)[i] = o;
        }
    }
}

extern "C" void kernel_launch(void* const* d_in, const int* in_sizes, int n_in,
                              void* d_out, int out_size, void* d_ws, size_t ws_size,
                              hipStream_t stream) {
    const float* x   = (const float*)d_in[0];
    const float* Wkv = (const float*)d_in[1];
    const float* bkv = (const float*)d_in[2];
    float* out = (float*)d_out;

    const size_t vElems = (size_t)NB * LQ * CH;                 // 2M
    unsigned short* Vt2 = (unsigned short*)d_ws;                // 4 MB (tiled slots)
    unsigned short* Vc2 = Vt2 + vElems;                         // 4 MB (tiled slots)
    float* Lsum = (float*)(Vc2 + vElems);                       // 512 KB (MAXCH)
    unsigned short* Opart = (unsigned short*)(Lsum + (size_t)MAXCH * NB * LQ);

    // nchunk=8 -> attn grid 512 = 2 blocks/CU (LDS 64 KB each)
    int nchunk = MAXCH;
    const size_t fixed = 2 * vElems * 2 + (size_t)MAXCH * NB * LQ * 4;
    while (nchunk > 1 && fixed + (size_t)nchunk * NB * LQ * CH * 2 > ws_size) nchunk >>= 1;
    const int titers = (LQ / 64) / nchunk;

    prep_kernel<<<dim3(256), dim3(256), 0, stream>>>(x, Wkv, bkv, Vt2, Vc2);
    attn_kernel<<<dim3(64 * nchunk), dim3(256), 0, stream>>>(x, Vt2, Vc2, Opart, Lsum, titers);
    combine_kernel<<<dim3(512), dim3(256), 0, stream>>>(Opart, Lsum, out, nchunk);
}

// Round 9
// 121.465 us; speedup vs baseline: 2.0602x; 2.0602x over previous
//
#include <hip/hip_runtime.h>

#define LQ 4096
#define CH 128
#define NB 4
// log2(e)/sqrt(128): folded into Q so softmax = exp2(S)
#define QSCALE 0.12753139626233174f
#define MAXCH 8
#define TILE_HW 8192   // one 64-key tile in fragment-slot order: 16 KB = 8192 ushort

#if defined(__has_builtin)
#if __has_builtin(__builtin_amdgcn_mfma_f32_16x16x16bf16_1k)
#define HAVE_MFMA16 1
#endif
#endif

typedef __attribute__((ext_vector_type(8))) unsigned short ushort8;
typedef __attribute__((ext_vector_type(4))) unsigned short ushort4v;
typedef __attribute__((ext_vector_type(4))) short short4v;
typedef __attribute__((ext_vector_type(8))) __bf16 bf16x8;
typedef __attribute__((ext_vector_type(4))) float f32x4;

__device__ inline unsigned short f2bf(float f) {
    unsigned int u = __builtin_bit_cast(unsigned int, f);
    u += 0x7fffu + ((u >> 16) & 1u);   // round-to-nearest-even
    return (unsigned short)(u >> 16);
}
__device__ inline float bf2f(unsigned short h) {
    unsigned int u = (unsigned int)h << 16;
    return __builtin_bit_cast(float, u);
}
// pack two positive floats to bf16 pair, round-half-up
__device__ inline unsigned int bfpack2(float a, float b) {
    unsigned int ua = __builtin_bit_cast(unsigned int, a) + 0x8000u;
    unsigned int ub = __builtin_bit_cast(unsigned int, b) + 0x8000u;
    return (ua >> 16) | (ub & 0xffff0000u);
}
// async 16B/lane global->LDS DMA: dest = lds_base + lane*16 (wave-uniform base)
__device__ inline void gload_lds16(const unsigned short* g, unsigned short* l) {
    __builtin_amdgcn_global_load_lds(
        (const __attribute__((address_space(1))) unsigned int*)(g),
        (__attribute__((address_space(3))) unsigned int*)(l), 16, 0, 0);
}

// ---------------------------------------------------------------------------
// Kernel 1: v = W_kv @ x (+bias), MFMA; emit Vt2/Vc2 in FRAGMENT-SLOT order:
//   Vt2[b][T][g=nt*4+kc][lane=quad*16+l16] (16B) = V[t=64T+16nt+l16][c=32kc+8quad..+8]
//   Vc2[b][T][g=nt*4+p ][lane]             (16B) = [V[c=32p+l16][t4] | V[c=32p+16+l16][t4]],
//                                                   t4 = 64T+16nt+4quad..+4
// so attn can DMA them straight into LDS and read b128 at base+lane*16.
// ---------------------------------------------------------------------------
__global__ __launch_bounds__(256) void prep_kernel(
    const float* __restrict__ x, const float* __restrict__ Wkv,
    const float* __restrict__ bkv,
    unsigned short* __restrict__ Vt2, unsigned short* __restrict__ Vc2)
{
    __shared__ __align__(16) unsigned short xs[64 * 136];  // [l][c] bf16
    __shared__ __align__(16) unsigned short vs[128 * 72];  // [o][l] bf16
    const int tid = threadIdx.x;
    const int lane = tid & 63;
    const int wave = tid >> 6;
    const int quad = lane >> 4, l16 = lane & 15;
    const int b = blockIdx.x & 3;
    const int T = blockIdx.x >> 2;
    const int l0 = T << 6;

    {   // stage x tile transposed: [64 l][128 c] bf16 (coalesced f32x4 loads)
        const f32x4* xg4 = (const f32x4*)(x + (size_t)b * CH * LQ + l0);
        #pragma unroll
        for (int i = 0; i < 8; ++i) {
            int idx = i * 256 + tid;          // 2048 chunks: c(128) x l4(16)
            int c = idx >> 4, l4 = idx & 15;
            f32x4 v = xg4[c * (LQ / 4) + l4];
            #pragma unroll
            for (int m = 0; m < 4; ++m) xs[(l4 * 4 + m) * 136 + c] = f2bf(v[m]);
        }
    }
    __syncthreads();

    const int wo = wave * 32;
    f32x4 acc[2][4];   // [ot][lt]
    #pragma unroll
    for (int ot = 0; ot < 2; ++ot)
        #pragma unroll
        for (int lt = 0; lt < 4; ++lt) acc[ot][lt] = f32x4{0.f, 0.f, 0.f, 0.f};

    #pragma unroll
    for (int kc = 0; kc < 4; ++kc) {
        bf16x8 af[2];
        #pragma unroll
        for (int ot = 0; ot < 2; ++ot) {
            const float* wrow = Wkv + (size_t)(wo + ot * 16 + l16) * CH + kc * 32 + quad * 8;
            ushort8 a;
            #pragma unroll
            for (int j = 0; j < 8; ++j) a[j] = f2bf(wrow[j]);
            af[ot] = __builtin_bit_cast(bf16x8, a);
        }
        #pragma unroll
        for (int lt = 0; lt < 4; ++lt) {
            bf16x8 bf = __builtin_bit_cast(bf16x8,
                *(const ushort8*)(xs + (lt * 16 + l16) * 136 + kc * 32 + quad * 8));
            #pragma unroll
            for (int ot = 0; ot < 2; ++ot)
                acc[ot][lt] = __builtin_amdgcn_mfma_f32_16x16x32_bf16(af[ot], bf, acc[ot][lt], 0, 0, 0);
        }
    }
    // bias + stage to vs[o][l] (C-layout: o = wo+ot*16+quad*4+r, l = lt*16+l16)
    #pragma unroll
    for (int ot = 0; ot < 2; ++ot) {
        float bias[4];
        #pragma unroll
        for (int r = 0; r < 4; ++r) bias[r] = bkv[wo + ot * 16 + quad * 4 + r];
        #pragma unroll
        for (int lt = 0; lt < 4; ++lt)
            #pragma unroll
            for (int r = 0; r < 4; ++r)
                vs[(wo + ot * 16 + quad * 4 + r) * 72 + lt * 16 + l16] =
                    f2bf(acc[ot][lt][r] + bias[r]);
    }
    __syncthreads();
    const size_t tbase = ((size_t)b * 64 + T) * TILE_HW;
    // Vt2: 1024 16B-chunks, 4/thread, consecutive tid -> consecutive 16B (coalesced)
    #pragma unroll
    for (int i = 0; i < 4; ++i) {
        const int ci = i * 256 + tid;
        const int g = ci >> 6, ls = ci & 63;
        const int nt = g >> 2, kc = g & 3, qs = ls >> 4, l16s = ls & 15;
        ushort8 v;
        #pragma unroll
        for (int j = 0; j < 8; ++j) v[j] = vs[(kc * 32 + qs * 8 + j) * 72 + nt * 16 + l16s];
        *(ushort8*)(Vt2 + tbase + (size_t)ci * 8) = v;
    }
    // Vc2: 1024 16B-chunks, nc-paired
    #pragma unroll
    for (int i = 0; i < 4; ++i) {
        const int ci = i * 256 + tid;
        const int g = ci >> 6, ls = ci & 63;
        const int nt = g >> 2, p = g & 3, qs = ls >> 4, l16s = ls & 15;
        ushort4v a = *(const ushort4v*)(vs + (p * 32 + l16s) * 72 + nt * 16 + qs * 4);
        ushort4v c2 = *(const ushort4v*)(vs + (p * 32 + 16 + l16s) * 72 + nt * 16 + qs * 4);
        ushort8 v;
        #pragma unroll
        for (int j = 0; j < 4; ++j) { v[j] = a[j]; v[j + 4] = c2[j]; }
        *(ushort8*)(Vc2 + tbase + (size_t)ci * 8) = v;
    }
}

// ---------------------------------------------------------------------------
// Kernel 2: flash attention, split-K, mt=2 (wave owns 32 q — r8's mt=4 blew
// the register budget and spilled 650 MB to scratch). Transposed-S chain
// (r6-verified math). Tiles arrive via global_load_lds DMA in fragment-slot
// order (double-buffered, ONE barrier per iter); every LDS read is
// ds_read_b128 at group_base + lane*16 (measured conflict-free in r8).
// ---------------------------------------------------------------------------
__global__ __launch_bounds__(256) void attn_kernel(
    const float* __restrict__ x, const unsigned short* __restrict__ Vt2,
    const unsigned short* __restrict__ Vc2,
    unsigned short* __restrict__ Opart, float* __restrict__ Lsum, int titers)
{
    __shared__ __align__(16) unsigned short bufA[2][TILE_HW];  // 32 KB
    __shared__ __align__(16) unsigned short bufB[2][TILE_HW];  // 32 KB
    const int tid = threadIdx.x;
    const int wave = tid >> 6, lane = tid & 63;
    const int quad = lane >> 4, l16 = lane & 15;
    const int b = blockIdx.x & 3;
    const int rest = blockIdx.x >> 2;
    const int qtile = rest & 31;           // 32 tiles of 128 q
    const int chunk = rest >> 5;           // nchunk split-K chunks
    const int q0w = (qtile << 7) + (wave << 5);
    const int Tbase = chunk * titers;

    const unsigned short* vtb = Vt2 + (size_t)b * 64 * TILE_HW;
    const unsigned short* vcb = Vc2 + (size_t)b * 64 * TILE_HW;

    // Q B-frags from x: B[n=l16 -> q][k=quad*8+j -> c], scaled (one-time)
    bf16x8 qf[2][4];
    #pragma unroll
    for (int mt = 0; mt < 2; ++mt)
        #pragma unroll
        for (int kc = 0; kc < 4; ++kc) {
            ushort8 v;
            #pragma unroll
            for (int j = 0; j < 8; ++j) {
                int c = kc * 32 + quad * 8 + j;
                v[j] = f2bf(x[((size_t)b * CH + c) * LQ + q0w + mt * 16 + l16] * QSCALE);
            }
            qf[mt][kc] = __builtin_bit_cast(bf16x8, v);
        }

    f32x4 oacc[2][8];
    #pragma unroll
    for (int mt = 0; mt < 2; ++mt)
        #pragma unroll
        for (int i = 0; i < 8; ++i) oacc[mt][i] = f32x4{0.f, 0.f, 0.f, 0.f};
    float lsum[2] = {0.f, 0.f};

    // DMA issue: wave w stages groups w*4..w*4+3 of each tensor (8 instr/wave)
    auto issue = [&](int T, int nb) {
        const unsigned short* sa = vtb + (size_t)T * TILE_HW + lane * 8;
        const unsigned short* sb = vcb + (size_t)T * TILE_HW + lane * 8;
        #pragma unroll
        for (int g = 0; g < 4; ++g) {
            const int go = (wave * 4 + g) * 512;
            gload_lds16(sa + go, &bufA[nb][go]);
            gload_lds16(sb + go, &bufB[nb][go]);
        }
    };
    issue(Tbase, 0);

    for (int it = 0; it < titers; ++it) {
        __syncthreads();   // drains own DMA (vmcnt0) + publishes buf[it&1]
        if (it + 1 < titers) issue(Tbase + it + 1, (it + 1) & 1);
        const unsigned short* A = bufA[it & 1];
        const unsigned short* B = bufB[it & 1];
        #pragma unroll
        for (int nt = 0; nt < 4; ++nt) {
            // V A-frags: conflict-free b128 at group base + lane*16
            bf16x8 vA[4];
            #pragma unroll
            for (int kc = 0; kc < 4; ++kc)
                vA[kc] = __builtin_bit_cast(bf16x8,
                    *(const ushort8*)(A + (nt * 4 + kc) * 512 + lane * 8));
            // S^T: D[m=t][n=q]; lane: q=l16, t=nt*16+quad*4+r
            f32x4 s[2];
            #pragma unroll
            for (int mt = 0; mt < 2; ++mt) {
                s[mt] = f32x4{0.f, 0.f, 0.f, 0.f};
                #pragma unroll
                for (int kc = 0; kc < 4; ++kc)
                    s[mt] = __builtin_amdgcn_mfma_f32_16x16x32_bf16(vA[kc], qf[mt][kc], s[mt], 0, 0, 0);
            }
            // exp2 + pack P as PV A-operand (k=quad*4+j matches t layout)
#ifdef HAVE_MFMA16
            short4v pf[2];
#else
            bf16x8 pf[2];
#endif
            #pragma unroll
            for (int mt = 0; mt < 2; ++mt) {
                float p0 = __builtin_amdgcn_exp2f(s[mt][0]);
                float p1 = __builtin_amdgcn_exp2f(s[mt][1]);
                float p2 = __builtin_amdgcn_exp2f(s[mt][2]);
                float p3 = __builtin_amdgcn_exp2f(s[mt][3]);
                lsum[mt] += (p0 + p1) + (p2 + p3);
                unsigned int lo = bfpack2(p0, p1);
                unsigned int hi = bfpack2(p2, p3);
#ifdef HAVE_MFMA16
                ushort4v pk;
                pk[0] = (unsigned short)lo; pk[1] = (unsigned short)(lo >> 16);
                pk[2] = (unsigned short)hi; pk[3] = (unsigned short)(hi >> 16);
                pf[mt] = __builtin_bit_cast(short4v, pk);
#else
                ushort8 pk;
                pk[0] = (unsigned short)lo; pk[1] = (unsigned short)(lo >> 16);
                pk[2] = (unsigned short)hi; pk[3] = (unsigned short)(hi >> 16);
                pk[4] = 0; pk[5] = 0; pk[6] = 0; pk[7] = 0;
                pf[mt] = __builtin_bit_cast(bf16x8, pk);
#endif
            }
            // PV: nc-paired b128 reads; B[k=quad*4+j][n=c=l16]
            #pragma unroll
            for (int p = 0; p < 4; ++p) {
                ushort8 d8 = *(const ushort8*)(B + (nt * 4 + p) * 512 + lane * 8);
                #pragma unroll
                for (int h = 0; h < 2; ++h) {
                    ushort4v f;
                    #pragma unroll
                    for (int j = 0; j < 4; ++j) f[j] = d8[h * 4 + j];
#ifdef HAVE_MFMA16
                    short4v vB = __builtin_bit_cast(short4v, f);
                    #pragma unroll
                    for (int mt = 0; mt < 2; ++mt)
                        oacc[mt][p * 2 + h] = __builtin_amdgcn_mfma_f32_16x16x16bf16_1k(
                            pf[mt], vB, oacc[mt][p * 2 + h], 0, 0, 0);
#else
                    ushort8 vb;
                    #pragma unroll
                    for (int j = 0; j < 4; ++j) { vb[j] = f[j]; vb[j + 4] = 0; }
                    bf16x8 vB = __builtin_bit_cast(bf16x8, vb);
                    #pragma unroll
                    for (int mt = 0; mt < 2; ++mt)
                        oacc[mt][p * 2 + h] = __builtin_amdgcn_mfma_f32_16x16x32_bf16(
                            pf[mt], vB, oacc[mt][p * 2 + h], 0, 0, 0);
#endif
                }
            }
        }
    }
    // ---- Lsum: per-lane partial (q=l16), reduce across the 4 quads ----
    const size_t pbase = ((size_t)(chunk * NB + b) * LQ);
    #pragma unroll
    for (int mt = 0; mt < 2; ++mt) {
        float v = lsum[mt];
        v += __shfl_xor(v, 16);
        v += __shfl_xor(v, 32);
        if (lane < 16) Lsum[pbase + q0w + mt * 16 + lane] = v;
    }
    // ---- partials: Opart[ch][b][q][c] (bf16); oacc lane: q=quad*4+r, c=l16
    #pragma unroll
    for (int mt = 0; mt < 2; ++mt)
        #pragma unroll
        for (int r = 0; r < 4; ++r) {
            const int q = q0w + mt * 16 + quad * 4 + r;
            unsigned short* orow = Opart + (pbase + q) * CH + l16;
            #pragma unroll
            for (int nc = 0; nc < 8; ++nc) orow[nc * 16] = f2bf(oacc[mt][nc][r]);
        }
}

// ---------------------------------------------------------------------------
// Kernel 3: out[b][c][q] = sum_ch Opart[ch][b][q][c] / sum_ch Lsum[ch][b][q]
// 512 blocks: (b, 32-q tile). LDS transpose.
// ---------------------------------------------------------------------------
__global__ __launch_bounds__(256) void combine_kernel(
    const unsigned short* __restrict__ Opart, const float* __restrict__ Lsum,
    float* __restrict__ out, int nchunk)
{
    __shared__ __align__(16) float ls[32 * 132];   // [q][c] padded
    __shared__ float linv[32];
    const int tid = threadIdx.x;
    const int b = blockIdx.x & 3;
    const int q0 = (blockIdx.x >> 2) << 5;

    if (tid < 32) {
        float s = 0.f;
        for (int ch = 0; ch < nchunk; ++ch) s += Lsum[(size_t)(ch * NB + b) * LQ + q0 + tid];
        linv[tid] = 1.0f / s;
    }
    __syncthreads();
    {
        const int c8 = (tid & 15) * 8, qg = tid >> 4;   // 16 q-groups x 2 q
        #pragma unroll
        for (int i = 0; i < 2; ++i) {
            const int q = qg * 2 + i;
            float s[8];
            #pragma unroll
            for (int k = 0; k < 8; ++k) s[k] = 0.f;
            for (int ch = 0; ch < nchunk; ++ch) {
                ushort8 p = *(const ushort8*)(Opart +
                    ((size_t)(ch * NB + b) * LQ + q0 + q) * CH + c8);
                #pragma unroll
                for (int k = 0; k < 8; ++k) s[k] += bf2f(p[k]);
            }
            const float li = linv[q];
            f32x4 o0, o1;
            #pragma unroll
            for (int k = 0; k < 4; ++k) { o0[k] = s[k] * li; o1[k] = s[k + 4] * li; }
            *(f32x4*)(ls + q * 132 + c8) = o0;
            *(f32x4*)(ls + q * 132 + c8 + 4) = o1;
        }
    }
    __syncthreads();
    {
        const int c = tid & 127, qh = tid >> 7;   // 2 halves of 16 q
        float* dst = out + ((size_t)b * CH + c) * LQ + q0 + qh * 16;
        #pragma unroll
        for (int i = 0; i < 4; ++i) {
            f32x4 o;
            #pragma unroll
            for (int r = 0; r < 4; ++r) o[r] = ls[(qh * 16 + i * 4 + r) * 132 + c];
            ((f32x4*)dst)[i] = o;
        }
    }
}

extern "C" void kernel_launch(void* const* d_in, const int* in_sizes, int n_in,
                              void* d_out, int out_size, void* d_ws, size_t ws_size,
                              hipStream_t stream) {
    const float* x   = (const float*)d_in[0];
    const float* Wkv = (const float*)d_in[1];
    const float* bkv = (const float*)d_in[2];
    float* out = (float*)d_out;

    const size_t vElems = (size_t)NB * LQ * CH;                 // 2M
    unsigned short* Vt2 = (unsigned short*)d_ws;                // 4 MB (tiled slots)
    unsigned short* Vc2 = Vt2 + vElems;                         // 4 MB (tiled slots)
    float* Lsum = (float*)(Vc2 + vElems);                       // 512 KB (MAXCH)
    unsigned short* Opart = (unsigned short*)(Lsum + (size_t)MAXCH * NB * LQ);

    // nchunk=4 -> attn grid 512 = exactly 2 blocks/CU (LDS 64 KB each)
    int nchunk = 4;
    const size_t fixed = 2 * vElems * 2 + (size_t)MAXCH * NB * LQ * 4;
    while (nchunk > 1 && fixed + (size_t)nchunk * NB * LQ * CH * 2 > ws_size) nchunk >>= 1;
    const int titers = (LQ / 64) / nchunk;

    prep_kernel<<<dim3(256), dim3(256), 0, stream>>>(x, Wkv, bkv, Vt2, Vc2);
    attn_kernel<<<dim3(128 * nchunk), dim3(256), 0, stream>>>(x, Vt2, Vc2, Opart, Lsum, titers);
    combine_kernel<<<dim3(512), dim3(256), 0, stream>>>(Opart, Lsum, out, nchunk);
}